// Round 9
// baseline (2991.614 us; speedup 1.0000x reference)
//
#include <hip/hip_runtime.h>
#include <stdint.h>
#include <stddef.h>

// ---------------------------------------------------------------------------
// TextRNN: embed -> BiLSTM(512 steps) -> linear -> softmax   (MI355X gfx950)
//
// K0: transpose/cast Wx,Wh (f32 [256][1024]) -> bf16 [1024][256]  (col-major)
// K1: one wg computes BOTH dirs for a time-slot (same emb gather); 256-col
//     tiles; emb rows staged in LDS bf16. Gather redundancy 32x -> 4x.
// K2: R9 sync: FLAG-based, low-traffic. R2/R3/R8 evidence says poll TRAFFIC
//     (16KB/wave/round of sc1 tag-polls), not RT count, dominates: R8's
//     drain-removal increased spin volume and regressed (2380 vs 1824).
//     New protocol per step t (per wave, no in-loop __syncthreads):
//       issue zx loads -> poll 64B flag line (1 dword/lane, sc1) until
//       __all(flags[d][w][0..15] >= t) -> ONE h burst (16x dwordx4 sc1,
//       committed data, no tag checks) -> MFMA/gates -> 4 data stores ->
//       vmcnt(0) drain -> lane0 stores flags[d][w][s]=t+1.
//     Safety: producer wave w's rows are read only by consumer waves w;
//     drain-before-flag orders data<flag; flag skew bounded at 1 step ->
//     double buffer can't be overwritten early. Poll traffic/step: 2MB->8KB.
//     (R4/R5 lesson: sc0/XCD-local exchange serves stale lines - never.)
// K3: logits = [h_f|h_b] @ W_out + b_out; softmax -> d_out (f32 64x10)
// ---------------------------------------------------------------------------

typedef __attribute__((ext_vector_type(8))) short   short8;
typedef __attribute__((ext_vector_type(4))) float   f32x4;
typedef __attribute__((ext_vector_type(4))) unsigned short ushort4v;
typedef __attribute__((ext_vector_type(4))) unsigned int   uint4v;
typedef __attribute__((ext_vector_type(2))) unsigned int   uint2v;

// ws byte offsets
#define ZX_OFF    ((size_t)0)                        // 2*512*1024*64 bf16 = 134217728 B
#define WXT_OFF   ((size_t)134217728)                // 2*1024*256 bf16    = 1048576 B
#define WHT_OFF   ((size_t)135266304)                // 2*1024*256 bf16    = 1048576 B
#define HBUF_OFF  ((size_t)136314880)                // 2 dir * 2 buf * 64*256 u32 = 262144 B
#define FLAGS_OFF ((size_t)136577024)                // [2][4][16] u32 = 512 B
#define WS_NEED   ((size_t)136577536)

__device__ __forceinline__ unsigned short f2bf(float f) {
  unsigned int u = __builtin_bit_cast(unsigned int, f);
  u += 0x7fffu + ((u >> 16) & 1u);            // RNE
  return (unsigned short)(u >> 16);
}
__device__ __forceinline__ float bf2f(unsigned short b) {
  unsigned int u = ((unsigned int)b) << 16;
  return __builtin_bit_cast(float, u);
}
__device__ __forceinline__ float sigf(float x) { return 1.0f / (1.0f + __expf(-x)); }
__device__ __forceinline__ float tanhf_(float x) {
  float t = __expf(-2.0f * fabsf(x));
  float r = (1.0f - t) / (1.0f + t);          // no inf/NaN for any x
  return copysignf(r, x);
}

// ---------------------------------------------------------------------------
// K0: W (f32 [256][1024]) -> Wt (bf16 [1024][256]).  z selects matrix.
__global__ __launch_bounds__(256) void k0_transpose(
    const float* __restrict__ wxf, const float* __restrict__ wxb,
    const float* __restrict__ whf, const float* __restrict__ whb,
    unsigned short* __restrict__ wxt, unsigned short* __restrict__ wht) {
  __shared__ float lds[32][33];
  int mat = blockIdx.z;
  const float* src = (mat == 0) ? wxf : (mat == 1) ? wxb : (mat == 2) ? whf : whb;
  unsigned short* dst = (mat == 0) ? wxt : (mat == 1) ? (wxt + 262144)
                      : (mat == 2) ? wht : (wht + 262144);
  int k0 = blockIdx.x * 32;
  int n0 = blockIdx.y * 32;
  int tx = threadIdx.x & 31, ty = threadIdx.x >> 5;   // ty 0..7
#pragma unroll
  for (int r = 0; r < 4; r++) {
    int k = ty + r * 8;
    lds[k][tx] = src[(size_t)(k0 + k) * 1024 + n0 + tx];
  }
  __syncthreads();
#pragma unroll
  for (int r = 0; r < 4; r++) {
    int n = ty + r * 8;
    dst[(size_t)(n0 + n) * 256 + k0 + tx] = f2bf(lds[tx][n]);
  }
}

// ---------------------------------------------------------------------------
// K1: both dirs per wg. grid (512 ts, 4 ct), block 256 (4 waves).
// Tile: 64 batches x 256 cols x 2 dirs.  zx[d][t][col][b] bf16.
__global__ __launch_bounds__(256) void k1_zx(
    const int* __restrict__ tokens, const float* __restrict__ emb,
    const unsigned short* __restrict__ wxt,   // [2][1024][256] bf16
    const float* __restrict__ bf_, const float* __restrict__ bb_,
    unsigned short* __restrict__ zx) {        // [2][512][1024][64] bf16
  int ts = blockIdx.x;
  int ct = blockIdx.y;
  int tid = threadIdx.x;
  int w = tid >> 6, lane = tid & 63, q = lane >> 4, l16 = lane & 15;

  __shared__ unsigned short el[64][264];      // emb rows, bf16, padded
  {
    int row = tid >> 2, qq = tid & 3;         // 4 threads per row
    int tok = tokens[row * 512 + ts];
    const float* er = emb + (size_t)tok * 256 + qq * 64;
#pragma unroll
    for (int c = 0; c < 8; c++) {
      f32x4 v0 = *(const f32x4*)(er + c * 8);
      f32x4 v1 = *(const f32x4*)(er + c * 8 + 4);
      short8 pk;
#pragma unroll
      for (int j = 0; j < 4; j++) {
        pk[j]     = (short)f2bf(v0[j]);
        pk[4 + j] = (short)f2bf(v1[j]);
      }
      *(short8*)(&el[row][qq * 64 + c * 8]) = pk;
    }
  }
  __syncthreads();

  // A-fragments (shared by both dirs): batches [16w,16w+16)
  short8 afr[8];
#pragma unroll
  for (int kt = 0; kt < 8; kt++)
    afr[kt] = *(const short8*)(&el[16 * w + l16][kt * 32 + q * 8]);

#pragma unroll
  for (int d = 0; d < 2; d++) {
    const unsigned short* wxd = wxt + (size_t)d * 262144;
    const float* bias = d ? bb_ : bf_;
    f32x4 acc[16];
#pragma unroll
    for (int cs = 0; cs < 16; cs++) acc[cs] = {0.f, 0.f, 0.f, 0.f};
#pragma unroll
    for (int kt = 0; kt < 8; kt++) {
      int kbase = kt * 32 + q * 8;
#pragma unroll
      for (int cs = 0; cs < 16; cs++) {
        int col = ct * 256 + cs * 16 + l16;
        short8 bfrag = *(const short8*)(wxd + (size_t)col * 256 + kbase);
        acc[cs] = __builtin_amdgcn_mfma_f32_16x16x32_bf16(afr[kt], bfrag, acc[cs], 0, 0, 0);
      }
    }
    int tdst = d ? (511 - ts) : ts;
#pragma unroll
    for (int cs = 0; cs < 16; cs++) {
      int col = ct * 256 + cs * 16 + l16;
      float bv = bias[col];
      ushort4v st;
#pragma unroll
      for (int r = 0; r < 4; r++) st[r] = f2bf(acc[cs][r] + bv);
      size_t idx = ((size_t)(d * 512 + tdst) * 1024 + col) * 64 + (w * 16 + q * 4);
      *(ushort4v*)(zx + idx) = st;
    }
  }
}

// ---------------------------------------------------------------------------
// 16 sc1 dwordx4 loads of the h set (offsets kt*128 + {0,16}) + drain.
#define LOAD_H16                                                 \
      "global_load_dwordx4 %[a0], %[p], off sc1\n\t"             \
      "global_load_dwordx4 %[b0], %[p], off offset:16 sc1\n\t"   \
      "global_load_dwordx4 %[a1], %[p], off offset:128 sc1\n\t"  \
      "global_load_dwordx4 %[b1], %[p], off offset:144 sc1\n\t"  \
      "global_load_dwordx4 %[a2], %[p], off offset:256 sc1\n\t"  \
      "global_load_dwordx4 %[b2], %[p], off offset:272 sc1\n\t"  \
      "global_load_dwordx4 %[a3], %[p], off offset:384 sc1\n\t"  \
      "global_load_dwordx4 %[b3], %[p], off offset:400 sc1\n\t"  \
      "global_load_dwordx4 %[a4], %[p], off offset:512 sc1\n\t"  \
      "global_load_dwordx4 %[b4], %[p], off offset:528 sc1\n\t"  \
      "global_load_dwordx4 %[a5], %[p], off offset:640 sc1\n\t"  \
      "global_load_dwordx4 %[b5], %[p], off offset:656 sc1\n\t"  \
      "global_load_dwordx4 %[a6], %[p], off offset:768 sc1\n\t"  \
      "global_load_dwordx4 %[b6], %[p], off offset:784 sc1\n\t"  \
      "global_load_dwordx4 %[a7], %[p], off offset:896 sc1\n\t"  \
      "global_load_dwordx4 %[b7], %[p], off offset:912 sc1\n\t"  \
      "s_waitcnt vmcnt(0)"

// EARLY-CLOBBER (=&v): async load results must never alias address regs (R7!)
#define OUTS_H16(A, B)                                                     \
      [a0] "=&v"(A[0]), [b0] "=&v"(B[0]), [a1] "=&v"(A[1]),                \
      [b1] "=&v"(B[1]), [a2] "=&v"(A[2]), [b2] "=&v"(B[2]),                \
      [a3] "=&v"(A[3]), [b3] "=&v"(B[3]), [a4] "=&v"(A[4]),                \
      [b4] "=&v"(B[4]), [a5] "=&v"(A[5]), [b5] "=&v"(B[5]),                \
      [a6] "=&v"(A[6]), [b6] "=&v"(B[6]), [a7] "=&v"(A[7]),                \
      [b7] "=&v"(B[7])

// K2: recurrence. 32 blocks (16/dir), 256 thr. Each wg owns 16 h-dims
// (cols gate-major: all 4 gates of (b,j) in one lane -> c-state in regs).
__global__ __launch_bounds__(256) void k2_rnn(
    const unsigned short* __restrict__ zx,    // [2][512][1024][64] bf16
    const unsigned short* __restrict__ wht,   // [2][1024][256] bf16
    unsigned int* __restrict__ hbufw,         // [2][2][64][256] u32 tagged
    unsigned int* __restrict__ flags) {       // [2][4][16] u32
  int d = blockIdx.x >> 4;
  int s = blockIdx.x & 15;
  int hdbase = s * 16;
  int tid = threadIdx.x;
  int w = tid >> 6, lane = tid & 63, q = lane >> 4, l16 = lane & 15;

  __shared__ unsigned short whtl[64][264];    // 33 KB, padded stride
  const unsigned short* whd = wht + (size_t)d * 262144;
  for (int idx = tid; idx < 2048; idx += 256) {
    int c = idx >> 5, kc = idx & 31;
    int grow = (c >> 4) * 256 + hdbase + (c & 15);    // gate*256 + hd
    *(short8*)(&whtl[c][kc * 8]) = *(const short8*)(whd + (size_t)grow * 256 + kc * 8);
  }
  __syncthreads();

  float cst[4] = {0.f, 0.f, 0.f, 0.f};        // c-state for (b=w*16+q*4+r, j=l16)
  unsigned int* hb = hbufw + (size_t)d * 32768;           // words
  int rowoff = (w * 16 + l16) * 256 + q * 8;              // consumer base (words)
  int srow   = (w * 16 + q * 4) * 256 + hdbase + l16;     // producer base (words)
  const unsigned short* zxd = zx + (size_t)d * 512 * 65536;
  const unsigned int* fp = flags + ((d * 4 + w) * 16 + l16);  // poll addr
  unsigned int*       fs = flags + ((d * 4 + w) * 16 + s);    // publish addr

  uint4v hA[8], hB[8];
  uint2v zr[4];

  for (int t = 0; t < 512; t++) {
    // zx loads first (plain cached, 4x8B); latency hides under the flag wait
    const unsigned short* zb = zxd + (size_t)t * 65536
                             + (size_t)(hdbase + l16) * 64 + (w * 16 + q * 4);
    asm volatile(
        "global_load_dwordx2 %[z0], %[pz0], off\n\t"
        "global_load_dwordx2 %[z1], %[pz1], off\n\t"
        "global_load_dwordx2 %[z2], %[pz2], off\n\t"
        "global_load_dwordx2 %[z3], %[pz3], off"
        : [z0] "=&v"(zr[0]), [z1] "=&v"(zr[1]),
          [z2] "=&v"(zr[2]), [z3] "=&v"(zr[3])
        : [pz0] "v"(zb), [pz1] "v"(zb + 16384),
          [pz2] "v"(zb + 32768), [pz3] "v"(zb + 49152)
        : "memory");

    // flag wait: h_t valid when all 16 producer-wave flags >= t.
    // 1 dword/lane (lanes 16+ mirror l16) -> 64B/round vs 16KB data-polling.
    unsigned int tt = (unsigned int)t;
    while (true) {
      unsigned int fv;
      asm volatile("global_load_dword %[f], %[p], off sc1\n\t"
                   "s_waitcnt vmcnt(0)"
                   : [f] "=&v"(fv) : [p] "v"(fp) : "memory");
      if (__all(fv >= tt)) break;
    }

    // single h burst -- data is committed (drain-before-flag), no tag checks
    const unsigned int* hp = hb + (t & 1) * 16384 + rowoff;
    asm volatile(LOAD_H16 : OUTS_H16(hA, hB) : [p] "v"(hp) : "memory");

    f32x4 acc[4];
#pragma unroll
    for (int cs = 0; cs < 4; cs++) {
      ushort4v zv = __builtin_bit_cast(ushort4v, zr[cs]);
#pragma unroll
      for (int r = 0; r < 4; r++) acc[cs][r] = bf2f(zv[r]);
    }

#pragma unroll
    for (int kt = 0; kt < 8; kt++) {
      // pack 8 tagged words -> 8 bf16 (v_perm_b32, low halves)
      uint4v pk;
      pk[0] = __builtin_amdgcn_perm(hA[kt][1], hA[kt][0], 0x05040100u);
      pk[1] = __builtin_amdgcn_perm(hA[kt][3], hA[kt][2], 0x05040100u);
      pk[2] = __builtin_amdgcn_perm(hB[kt][1], hB[kt][0], 0x05040100u);
      pk[3] = __builtin_amdgcn_perm(hB[kt][3], hB[kt][2], 0x05040100u);
      short8 afrag = __builtin_bit_cast(short8, pk);
      int kbase = kt * 32 + q * 8;
#pragma unroll
      for (int cs = 0; cs < 4; cs++) {
        short8 bfrag = *(const short8*)(&whtl[cs * 16 + l16][kbase]);
        acc[cs] = __builtin_amdgcn_mfma_f32_16x16x32_bf16(afrag, bfrag, acc[cs], 0, 0, 0);
      }
    }

    unsigned int* hwn = hb + ((t + 1) & 1) * 16384 + srow;
    unsigned int wtag = ((unsigned int)(t + 1)) << 16;
    unsigned int sw[4];
#pragma unroll
    for (int r = 0; r < 4; r++) {
      float iv = sigf(acc[0][r]);
      float fv_ = sigf(acc[1][r]);
      float gv = tanhf_(acc[2][r]);
      float ov = sigf(acc[3][r]);
      cst[r] = fv_ * cst[r] + iv * gv;
      float hv = ov * tanhf_(cst[r]);
      sw[r] = wtag | (unsigned int)f2bf(hv);
    }
    // data stores (rows at word-stride 256 = 1024 B) -> drain -> flag store.
    // Drain is mandatory: it orders data < flag at the coherence point.
    asm volatile(
        "global_store_dword %[p], %[v0], off sc1\n\t"
        "global_store_dword %[p], %[v1], off offset:1024 sc1\n\t"
        "global_store_dword %[p], %[v2], off offset:2048 sc1\n\t"
        "global_store_dword %[p], %[v3], off offset:3072 sc1\n\t"
        "s_waitcnt vmcnt(0)"
        :: [p] "v"(hwn), [v0] "v"(sw[0]), [v1] "v"(sw[1]),
           [v2] "v"(sw[2]), [v3] "v"(sw[3])
        : "memory");
    if (lane == 0) {
      unsigned int tv = (unsigned int)(t + 1);
      asm volatile("global_store_dword %[p], %[v], off sc1"
                   :: [p] "v"(fs), [v] "v"(tv) : "memory");
    }
  }
}

// ---------------------------------------------------------------------------
// K3: logits + softmax. 64 blocks (one per batch) x 64 threads (one wave).
// Final h_512 sits in buf0 of each dir (tagged words; low16 = bf16 value).
__global__ __launch_bounds__(64) void k3_out(
    const unsigned int* __restrict__ hbufw,
    const float* __restrict__ wout, const float* __restrict__ bout,
    float* __restrict__ out) {
  int b = blockIdx.x, tid = threadIdx.x;
  const unsigned int* hf  = hbufw;            // dir0 buf0
  const unsigned int* hbk = hbufw + 32768;    // dir1 buf0
  float p[10];
#pragma unroll
  for (int l = 0; l < 10; l++) p[l] = 0.f;
  for (int k = tid; k < 512; k += 64) {
    unsigned int wd = (k < 256) ? hf[b * 256 + k] : hbk[b * 256 + k - 256];
    float f = bf2f((unsigned short)(wd & 0xffffu));
    const float* wr = wout + k * 10;
#pragma unroll
    for (int l = 0; l < 10; l++) p[l] += f * wr[l];
  }
#pragma unroll
  for (int off = 32; off; off >>= 1)
#pragma unroll
    for (int l = 0; l < 10; l++) p[l] += __shfl_down(p[l], off);
  if (tid == 0) {
    float lg[10], m = -1e30f;
#pragma unroll
    for (int l = 0; l < 10; l++) { lg[l] = p[l] + bout[l]; m = fmaxf(m, lg[l]); }
    float sum = 0.f;
#pragma unroll
    for (int l = 0; l < 10; l++) { lg[l] = __expf(lg[l] - m); sum += lg[l]; }
    float inv = 1.0f / sum;
#pragma unroll
    for (int l = 0; l < 10; l++) out[b * 10 + l] = lg[l] * inv;
  }
}

// ---------------------------------------------------------------------------
extern "C" void kernel_launch(void* const* d_in, const int* in_sizes, int n_in,
                              void* d_out, int out_size, void* d_ws, size_t ws_size,
                              hipStream_t stream) {
  const int*   tokens = (const int*)d_in[0];
  const float* emb    = (const float*)d_in[1];
  const float* wxf    = (const float*)d_in[2];
  const float* whf    = (const float*)d_in[3];
  const float* bf_    = (const float*)d_in[4];
  const float* wxb    = (const float*)d_in[5];
  const float* whb    = (const float*)d_in[6];
  const float* bb_    = (const float*)d_in[7];
  const float* wout   = (const float*)d_in[8];
  const float* bout   = (const float*)d_in[9];
  float* out = (float*)d_out;

  char* ws = (char*)d_ws;
  unsigned short* zx    = (unsigned short*)(ws + ZX_OFF);
  unsigned short* wxt   = (unsigned short*)(ws + WXT_OFF);
  unsigned short* wht   = (unsigned short*)(ws + WHT_OFF);
  unsigned int*   hbufw = (unsigned int*)(ws + HBUF_OFF);
  unsigned int*   flags = (unsigned int*)(ws + FLAGS_OFF);
  (void)ws_size; (void)in_sizes; (void)n_in; (void)out_size;   // needs WS_NEED bytes

  // zero h0 (tag 0) + flags (0 => h_0 valid at t=0); poison 0xAA... never
  // satisfies "flag >= t" checks wrongly since we overwrite it here.
  hipMemsetAsync(ws + HBUF_OFF, 0, 262144 + 512, stream);

  k0_transpose<<<dim3(8, 32, 4), 256, 0, stream>>>(wxf, wxb, whf, whb, wxt, wht);
  k1_zx<<<dim3(512, 4), 256, 0, stream>>>(tokens, emb, wxt, bf_, bb_, zx);
  k2_rnn<<<32, 256, 0, stream>>>(zx, wht, hbufw, flags);
  k3_out<<<64, 64, 0, stream>>>(hbufw, wout, bout, out);
}